// Round 8
// baseline (659.202 us; speedup 1.0000x reference)
//
#include <hip/hip_runtime.h>
#include <math.h>

// CRF forward partition scan. B=512, S=1024, T=48.
// One 64-lane wave per batch element. Lane j owns tag j (lanes 48..63 clamp).
//
// R3-R5 post-mortem: compiler grants only ~80 VGPRs regardless of source
// tricks; 96 loop-live constants (T+E) don't fit, so it re-loads/recomputes
// ~50/step (L1-hit remat: FETCH unchanged, WRITE~0, identical codegen x3).
// R6/R8: make demand fit the grant. E (48 vals) stays in registers; T moves
// to LDS, transposed, row stride 52 floats (16B-aligned; lane base banks
// step 20 mod 32 -> 8-lane groups tile all 32 banks, conflict-free at the
// 8-cyc b128 floor). Register demand ~75 <= ~80 grant -> nothing to remat.
//
// R6/R7 benches died with "container failed twice" (infra-shaped). Hedge:
// this resubmission drops the 48x `asm volatile` pins (the only exotic
// construct new since R5, and unnecessary: remat is pressure-driven, and
// demand now fits the grant). Everything else identical to R6.

constexpr int kB  = 512;
constexpr int kS  = 1024;
constexpr int kT  = 48;
constexpr int kTS = 52;   // Tt row stride in floats; 52*4=208 B, 16B-aligned

#define REP12(X) X(0) X(1) X(2) X(3) X(4) X(5) X(6) X(7) X(8) X(9) X(10) X(11)

// X(i, i/4, component, i%8)
#define REP48(X) \
  X(0,0,x,0)   X(1,0,y,1)   X(2,0,z,2)   X(3,0,w,3)   \
  X(4,1,x,4)   X(5,1,y,5)   X(6,1,z,6)   X(7,1,w,7)   \
  X(8,2,x,0)   X(9,2,y,1)   X(10,2,z,2)  X(11,2,w,3)  \
  X(12,3,x,4)  X(13,3,y,5)  X(14,3,z,6)  X(15,3,w,7)  \
  X(16,4,x,0)  X(17,4,y,1)  X(18,4,z,2)  X(19,4,w,3)  \
  X(20,5,x,4)  X(21,5,y,5)  X(22,5,z,6)  X(23,5,w,7)  \
  X(24,6,x,0)  X(25,6,y,1)  X(26,6,z,2)  X(27,6,w,3)  \
  X(28,7,x,4)  X(29,7,y,5)  X(30,7,z,6)  X(31,7,w,7)  \
  X(32,8,x,0)  X(33,8,y,1)  X(34,8,z,2)  X(35,8,w,3)  \
  X(36,9,x,4)  X(37,9,y,5)  X(38,9,z,6)  X(39,9,w,7)  \
  X(40,10,x,0) X(41,10,y,1) X(42,10,z,2) X(43,10,w,3) \
  X(44,11,x,4) X(45,11,y,5) X(46,11,z,6) X(47,11,w,7)

#define DECL_E(i,q,c,a)  float E##i;
#define INIT_TE(i,q,c,a) { const float t_ = trans[(i)*kT + j]; \
                           tt_sh[(size_t)j*kTS + (i)] = t_;     \
                           E##i = __expf(t_); }
#define LOADP(q)  const float4 P##q  = p4[q];
#define LOADT(q)  const float4 TT##q = t4j[q];
#define LOADQ(q)  const float4 Q##q  = q4[q];
#define PASS1(i,q,c,a) am##a = fmaxf(am##a, (TT##q).c + (P##q).c);
#define PASS2(i,q,c,a) as##a = fmaf(E##i, (Q##q).c, as##a);

__global__ __launch_bounds__(64, 1) void crf_fwd(
    const float* __restrict__ feats,   // [B, S, T] fp32
    const int*   __restrict__ mask,    // [B, S] int32 (bool)
    const float* __restrict__ trans,   // [T, T] fp32
    float*       __restrict__ out)     // [1 + B]; we write out[1+b]
{
    const int b    = blockIdx.x;
    const int lane = threadIdx.x;
    const int j    = (lane < kT) ? lane : (kT - 1);  // clamp idle lanes

    __shared__ alignas(16) float tt_sh[kT * kTS];  // Tt[j][i] = trans[i][j]
    __shared__ alignas(16) float p_sh[64];         // part_i
    __shared__ alignas(16) float ea_sh[64];        // exp(part_i - e_i - M_i)
    const float4* p4  = (const float4*)p_sh;
    const float4* q4  = (const float4*)ea_sh;
    const float4* t4j = (const float4*)(tt_sh + (size_t)j * kTS);

    // E column in 48 registers; T column into LDS (transposed).
    REP48(DECL_E)
    REP48(INIT_TE)

    const float* fb = feats + (size_t)b * kS * kT + j;  // lane-offset base
    const int*   mb = mask  + (size_t)b * kS;

    // part0 = emit[0] + transition[T-2, :]   (row 46, column j)
    float part = fb[0] + trans[(kT - 2) * kT + j];
    p_sh[lane] = part;
    __syncthreads();  // covers tt_sh writes + p_sh

    // Depth-4 register-rotated prefetch of (emission, mask).
    float e0 = fb[(size_t)1 * kT], e1 = fb[(size_t)2 * kT],
          e2 = fb[(size_t)3 * kT], e3 = fb[(size_t)4 * kT];
    int   m0 = mb[1], m1 = mb[2], m2 = mb[3], m3 = mb[4];

    for (int t = 1; t < kS; ++t) {
        const float e  = e0;
        const int   mk = m0;
        e0 = e1; e1 = e2; e2 = e3;
        m0 = m1; m1 = m2; m2 = m3;
        const int tn = (t + 4 < kS) ? (t + 4) : (kS - 1);
        e3 = fb[(size_t)tn * kT];
        m3 = mb[tn];

        if (mk) {  // wave-uniform branch: skip masked-out steps entirely
            const float pe = part - e;  // off the M-dependent critical path

            // pass 1: M_j = max_i (T[i,j] + part_i).
            // T column: 12 ds_read_b128 from this lane's Tt row.
            // p vector: 12 broadcast b128 reads (uniform address, cheap).
            REP12(LOADT)
            REP12(LOADP)
            float am0 = -INFINITY, am1 = -INFINITY, am2 = -INFINITY, am3 = -INFINITY;
            float am4 = -INFINITY, am5 = -INFINITY, am6 = -INFINITY, am7 = -INFINITY;
            REP48(PASS1)
            const float M = fmaxf(fmaxf(fmaxf(am0, am4), fmaxf(am1, am5)),
                                  fmaxf(fmaxf(am2, am6), fmaxf(am3, am7)));

            // lane i publishes exp(part_i - e_i - M_i)
            const float ea = __expf(pe - M);
            ea_sh[lane] = ea;
            __syncthreads();  // B1: ea visible; pass-1 reads of p_sh done

            // pass 2: S_j = sum_i exp(T[i,j]) * ea_i  (register-E FMA chain)
            REP12(LOADQ)
            float as0 = 0.f, as1 = 0.f, as2 = 0.f, as3 = 0.f;
            float as4 = 0.f, as5 = 0.f, as6 = 0.f, as7 = 0.f;
            REP48(PASS2)
            const float Ssum = ((as0 + as4) + (as1 + as5)) +
                               ((as2 + as6) + (as3 + as7));

            // val_j = 2*e_j + M_j + log(S_j); mask true so part <- val
            part = 2.0f * e + M + __logf(Ssum);
            p_sh[lane] = part;
            __syncthreads();  // B2: part visible for next step's pass 1
        }
    }

    // Final transition-only step; only end_value[:, T-1] is stored.
    {
        REP12(LOADT)
        REP12(LOADP)
        float am0 = -INFINITY, am1 = -INFINITY, am2 = -INFINITY, am3 = -INFINITY;
        float am4 = -INFINITY, am5 = -INFINITY, am6 = -INFINITY, am7 = -INFINITY;
        REP48(PASS1)
        const float M = fmaxf(fmaxf(fmaxf(am0, am4), fmaxf(am1, am5)),
                              fmaxf(fmaxf(am2, am6), fmaxf(am3, am7)));
        const float ea = __expf(part - M);   // no emission term in final step
        ea_sh[lane] = ea;
        __syncthreads();

        REP12(LOADQ)
        float as0 = 0.f, as1 = 0.f, as2 = 0.f, as3 = 0.f;
        float as4 = 0.f, as5 = 0.f, as6 = 0.f, as7 = 0.f;
        REP48(PASS2)
        const float Ssum = ((as0 + as4) + (as1 + as5)) +
                           ((as2 + as6) + (as3 + as7));
        const float val = M + __logf(Ssum);
        if (lane == kT - 1) out[1 + b] = val;  // score[b] = end_value[b, -1]
    }
}

// out[0] = sum(score). Single wave; no barriers needed.
__global__ __launch_bounds__(64) void sum_scores(
    const float* __restrict__ sc, float* __restrict__ out)
{
    float s = 0.f;
    for (int i = (int)threadIdx.x; i < kB; i += 64) s += sc[i];
#pragma unroll
    for (int off = 32; off > 0; off >>= 1) s += __shfl_down(s, off);
    if (threadIdx.x == 0) out[0] = s;
}

extern "C" void kernel_launch(void* const* d_in, const int* in_sizes, int n_in,
                              void* d_out, int out_size, void* d_ws, size_t ws_size,
                              hipStream_t stream) {
    const float* feats = (const float*)d_in[0];
    const int*   mask  = (const int*)d_in[1];
    const float* trans = (const float*)d_in[2];
    float*       out   = (float*)d_out;

    crf_fwd<<<dim3(kB), dim3(64), 0, stream>>>(feats, mask, trans, out);
    sum_scores<<<dim3(1), dim3(64), 0, stream>>>(out + 1, out);
}

// Round 9
// 626.778 us; speedup vs baseline: 1.0517x; 1.0517x over previous
//
#include <hip/hip_runtime.h>
#include <math.h>

// CRF forward partition scan. B=512, S=1024, T=48.
// One 64-lane wave per batch element. Lane j owns tag j (lanes 48..63 clamp).
//
// R8 post-mortem: 530-563us plateau across 5 register layouts; VALUBusy 18%
// => ~1500 cyc stall per active step. Cause: __syncthreads() twice per step.
// s_barrier semantics force `s_waitcnt vmcnt(0)` -> every step DRAINS the
// e/mask prefetch queue, putting one full global-load latency (~1000 cyc) on
// the serial chain. The workgroup is a SINGLE WAVE: LDS ops from one wave
// complete in order (ISA guarantee), so ds_write->ds_read RAW needs no
// barrier at all. R9: replace in-loop __syncthreads() with
// __builtin_amdgcn_wave_barrier() (compile-time scheduling fence, zero HW
// cost, no vmcnt drain). Prefetch now truly stays in flight across steps.
//
// Layout (from R8): E=exp(T col) in 48 regs; T transposed in LDS (row
// stride 52 floats, 16B-aligned), 12 ds_read_b128/step; p/ea exchanged
// through 64-float LDS arrays read as broadcast float4s.

constexpr int kB  = 512;
constexpr int kS  = 1024;
constexpr int kT  = 48;
constexpr int kTS = 52;   // Tt row stride in floats; 52*4=208 B, 16B-aligned

#define REP12(X) X(0) X(1) X(2) X(3) X(4) X(5) X(6) X(7) X(8) X(9) X(10) X(11)

// X(i, i/4, component, i%8)
#define REP48(X) \
  X(0,0,x,0)   X(1,0,y,1)   X(2,0,z,2)   X(3,0,w,3)   \
  X(4,1,x,4)   X(5,1,y,5)   X(6,1,z,6)   X(7,1,w,7)   \
  X(8,2,x,0)   X(9,2,y,1)   X(10,2,z,2)  X(11,2,w,3)  \
  X(12,3,x,4)  X(13,3,y,5)  X(14,3,z,6)  X(15,3,w,7)  \
  X(16,4,x,0)  X(17,4,y,1)  X(18,4,z,2)  X(19,4,w,3)  \
  X(20,5,x,4)  X(21,5,y,5)  X(22,5,z,6)  X(23,5,w,7)  \
  X(24,6,x,0)  X(25,6,y,1)  X(26,6,z,2)  X(27,6,w,3)  \
  X(28,7,x,4)  X(29,7,y,5)  X(30,7,z,6)  X(31,7,w,7)  \
  X(32,8,x,0)  X(33,8,y,1)  X(34,8,z,2)  X(35,8,w,3)  \
  X(36,9,x,4)  X(37,9,y,5)  X(38,9,z,6)  X(39,9,w,7)  \
  X(40,10,x,0) X(41,10,y,1) X(42,10,z,2) X(43,10,w,3) \
  X(44,11,x,4) X(45,11,y,5) X(46,11,z,6) X(47,11,w,7)

#define DECL_E(i,q,c,a)  float E##i;
#define INIT_TE(i,q,c,a) { const float t_ = trans[(i)*kT + j]; \
                           tt_sh[(size_t)j*kTS + (i)] = t_;     \
                           E##i = __expf(t_); }
#define LOADP(q)  const float4 P##q  = p4[q];
#define LOADT(q)  const float4 TT##q = t4j[q];
#define LOADQ(q)  const float4 Q##q  = q4[q];
#define PASS1(i,q,c,a) am##a = fmaxf(am##a, (TT##q).c + (P##q).c);
#define PASS2(i,q,c,a) as##a = fmaf(E##i, (Q##q).c, as##a);

// Single-wave workgroup "barrier": compiler scheduling fence only. The LDS
// pipe executes one wave's ds ops in order, so cross-lane RAW through LDS is
// already correct in hardware; we only forbid compiler reordering. No
// s_barrier -> no forced s_waitcnt vmcnt(0) -> prefetch survives the step.
__device__ __forceinline__ void wave_fence() {
    __builtin_amdgcn_wave_barrier();
}

__global__ __launch_bounds__(64, 1) void crf_fwd(
    const float* __restrict__ feats,   // [B, S, T] fp32
    const int*   __restrict__ mask,    // [B, S] int32 (bool)
    const float* __restrict__ trans,   // [T, T] fp32
    float*       __restrict__ out)     // [1 + B]; we write out[1+b]
{
    const int b    = blockIdx.x;
    const int lane = threadIdx.x;
    const int j    = (lane < kT) ? lane : (kT - 1);  // clamp idle lanes

    __shared__ alignas(16) float tt_sh[kT * kTS];  // Tt[j][i] = trans[i][j]
    __shared__ alignas(16) float p_sh[64];         // part_i
    __shared__ alignas(16) float ea_sh[64];        // exp(part_i - e_i - M_i)
    const float4* p4  = (const float4*)p_sh;
    const float4* q4  = (const float4*)ea_sh;
    const float4* t4j = (const float4*)(tt_sh + (size_t)j * kTS);

    // E column in 48 registers; T column into LDS (transposed).
    REP48(DECL_E)
    REP48(INIT_TE)

    const float* fb = feats + (size_t)b * kS * kT + j;  // lane-offset base
    const int*   mb = mask  + (size_t)b * kS;

    // part0 = emit[0] + transition[T-2, :]   (row 46, column j)
    float part = fb[0] + trans[(kT - 2) * kT + j];
    p_sh[lane] = part;
    wave_fence();   // order init tt_sh/p_sh writes before loop reads

    // Depth-4 register-rotated prefetch of (emission, mask). With no
    // s_barrier in the loop these loads genuinely stay in flight.
    float e0 = fb[(size_t)1 * kT], e1 = fb[(size_t)2 * kT],
          e2 = fb[(size_t)3 * kT], e3 = fb[(size_t)4 * kT];
    int   m0 = mb[1], m1 = mb[2], m2 = mb[3], m3 = mb[4];

    for (int t = 1; t < kS; ++t) {
        const float e  = e0;
        const int   mk = m0;
        e0 = e1; e1 = e2; e2 = e3;
        m0 = m1; m1 = m2; m2 = m3;
        const int tn = (t + 4 < kS) ? (t + 4) : (kS - 1);
        e3 = fb[(size_t)tn * kT];
        m3 = mb[tn];

        if (mk) {  // wave-uniform branch: skip masked-out steps entirely
            const float pe = part - e;  // off the M-dependent critical path

            // pass 1: M_j = max_i (T[i,j] + part_i).
            REP12(LOADT)
            REP12(LOADP)
            float am0 = -INFINITY, am1 = -INFINITY, am2 = -INFINITY, am3 = -INFINITY;
            float am4 = -INFINITY, am5 = -INFINITY, am6 = -INFINITY, am7 = -INFINITY;
            REP48(PASS1)
            const float M = fmaxf(fmaxf(fmaxf(am0, am4), fmaxf(am1, am5)),
                                  fmaxf(fmaxf(am2, am6), fmaxf(am3, am7)));

            // lane i publishes exp(part_i - e_i - M_i)
            const float ea = __expf(pe - M);
            wave_fence();         // reads of p_sh above precede ea_sh write
            ea_sh[lane] = ea;
            wave_fence();         // ea_sh write precedes LOADQ reads

            // pass 2: S_j = sum_i exp(T[i,j]) * ea_i  (register-E FMA chain)
            REP12(LOADQ)
            float as0 = 0.f, as1 = 0.f, as2 = 0.f, as3 = 0.f;
            float as4 = 0.f, as5 = 0.f, as6 = 0.f, as7 = 0.f;
            REP48(PASS2)
            const float Ssum = ((as0 + as4) + (as1 + as5)) +
                               ((as2 + as6) + (as3 + as7));

            // val_j = 2*e_j + M_j + log(S_j); mask true so part <- val
            part = 2.0f * e + M + __logf(Ssum);
            wave_fence();         // LOADQ reads precede p_sh overwrite
            p_sh[lane] = part;
            wave_fence();         // p_sh write precedes next step's LOADP
        }
    }

    // Final transition-only step; only end_value[:, T-1] is stored.
    {
        REP12(LOADT)
        REP12(LOADP)
        float am0 = -INFINITY, am1 = -INFINITY, am2 = -INFINITY, am3 = -INFINITY;
        float am4 = -INFINITY, am5 = -INFINITY, am6 = -INFINITY, am7 = -INFINITY;
        REP48(PASS1)
        const float M = fmaxf(fmaxf(fmaxf(am0, am4), fmaxf(am1, am5)),
                              fmaxf(fmaxf(am2, am6), fmaxf(am3, am7)));
        const float ea = __expf(part - M);   // no emission term in final step
        wave_fence();
        ea_sh[lane] = ea;
        wave_fence();

        REP12(LOADQ)
        float as0 = 0.f, as1 = 0.f, as2 = 0.f, as3 = 0.f;
        float as4 = 0.f, as5 = 0.f, as6 = 0.f, as7 = 0.f;
        REP48(PASS2)
        const float Ssum = ((as0 + as4) + (as1 + as5)) +
                           ((as2 + as6) + (as3 + as7));
        const float val = M + __logf(Ssum);
        if (lane == kT - 1) out[1 + b] = val;  // score[b] = end_value[b, -1]
    }
}

// out[0] = sum(score). Single wave; no barriers needed.
__global__ __launch_bounds__(64) void sum_scores(
    const float* __restrict__ sc, float* __restrict__ out)
{
    float s = 0.f;
    for (int i = (int)threadIdx.x; i < kB; i += 64) s += sc[i];
#pragma unroll
    for (int off = 32; off > 0; off >>= 1) s += __shfl_down(s, off);
    if (threadIdx.x == 0) out[0] = s;
}

extern "C" void kernel_launch(void* const* d_in, const int* in_sizes, int n_in,
                              void* d_out, int out_size, void* d_ws, size_t ws_size,
                              hipStream_t stream) {
    const float* feats = (const float*)d_in[0];
    const int*   mask  = (const int*)d_in[1];
    const float* trans = (const float*)d_in[2];
    float*       out   = (float*)d_out;

    crf_fwd<<<dim3(kB), dim3(64), 0, stream>>>(feats, mask, trans, out);
    sum_scores<<<dim3(1), dim3(64), 0, stream>>>(out + 1, out);
}

// Round 10
// 547.402 us; speedup vs baseline: 1.2042x; 1.1450x over previous
//
#include <hip/hip_runtime.h>
#include <math.h>

// CRF forward partition scan. B=512, S=1024, T=48.
// One 64-lane wave per batch element. Lane j owns tag j (lanes 48..63 clamp).
//
// R9 post-mortem: barrier/vm theories dead (barrier removal: -7%). Step time
// ~1700 cyc = ~480 cyc VALU issue + ~250 LDS + ~750 dep-stall slop. R10 cuts
// issued work + chain slop:
//  - mask via __ballot -> SGPR bitmask; per-step gate = s_and/s_lshr, no
//    memory, no m-prefetch rotation.
//  - packed f32 (v_pk_add/max/fma via float2 ext vectors +
//    __builtin_elementwise_*): pass1 96 -> 48 ops, pass2 48 -> 24 ops.
//  - E as 24 float2 pairs in regs (48 VGPRs, proven resident at the ~80
//    grant in R8/R9); T transposed in LDS (stride 52), b128 reads.

constexpr int kB  = 512;
constexpr int kS  = 1024;
constexpr int kT  = 48;
constexpr int kTS = 52;   // Tt row stride in floats; 52*4=208 B, 16B-aligned

typedef float v2 __attribute__((ext_vector_type(2)));
struct V2P { v2 lo, hi; };

#define REP12(X) X(0) X(1) X(2) X(3) X(4) X(5) X(6) X(7) X(8) X(9) X(10) X(11)

// X(k, i0, i1): EV pair k covers transition rows i0=2k, i1=2k+1
#define REP24(X) \
  X(0,0,1)    X(1,2,3)    X(2,4,5)    X(3,6,7) \
  X(4,8,9)    X(5,10,11)  X(6,12,13)  X(7,14,15) \
  X(8,16,17)  X(9,18,19)  X(10,20,21) X(11,22,23) \
  X(12,24,25) X(13,26,27) X(14,28,29) X(15,30,31) \
  X(16,32,33) X(17,34,35) X(18,36,37) X(19,38,39) \
  X(20,40,41) X(21,42,43) X(22,44,45) X(23,46,47)

// X(q, evA, evB, a, b): quad q (rows 4q..4q+3), EV pair ids, acc ids
#define REPQ(X) \
  X(0,0,1,0,3)    X(1,2,3,1,2)    X(2,4,5,2,1)    X(3,6,7,3,0) \
  X(4,8,9,0,3)    X(5,10,11,1,2)  X(6,12,13,2,1)  X(7,14,15,3,0) \
  X(8,16,17,0,3)  X(9,18,19,1,2)  X(10,20,21,2,1) X(11,22,23,3,0)

#define DECL_EV(k,i0,i1)  v2 EV##k;
#define INIT_EV(k,i0,i1) { const float tA_ = trans[(i0)*kT + j]; \
                           const float tB_ = trans[(i1)*kT + j]; \
                           tt_sh[(size_t)j*kTS + (i0)] = tA_;    \
                           tt_sh[(size_t)j*kTS + (i1)] = tB_;    \
                           EV##k = (v2){__expf(tA_), __expf(tB_)}; }

#define LOADP(q)  const float4 P##q  = p4[q];
#define LOADT(q)  const float4 TT##q = t4j[q];
#define LOADQ(q)  const float4 Q##q  = q4[q];

// pass 1: mv[a] = max(mv[a], T.lo + p.lo); mv[b] = max(mv[b], T.hi + p.hi)
#define PASS1(q,evA,evB,a,b) { \
    const V2P t_ = __builtin_bit_cast(V2P, TT##q); \
    const V2P p_ = __builtin_bit_cast(V2P, P##q);  \
    mv##a = __builtin_elementwise_max(mv##a, t_.lo + p_.lo); \
    mv##b = __builtin_elementwise_max(mv##b, t_.hi + p_.hi); }

// pass 2: sv[a] += EV[evA] * q.lo; sv[b] += EV[evB] * q.hi   (pk_fma)
#define PASS2(q,evA,evB,a,b) { \
    const V2P q_ = __builtin_bit_cast(V2P, Q##q); \
    sv##a = __builtin_elementwise_fma(EV##evA, q_.lo, sv##a); \
    sv##b = __builtin_elementwise_fma(EV##evB, q_.hi, sv##b); }

// Single-wave workgroup: LDS pipe is in-order per wave, so cross-lane RAW
// through LDS needs only a compiler scheduling fence, not s_barrier.
__device__ __forceinline__ void wave_fence() {
    __builtin_amdgcn_wave_barrier();
}

__global__ __launch_bounds__(64, 1) void crf_fwd(
    const float* __restrict__ feats,   // [B, S, T] fp32
    const int*   __restrict__ mask,    // [B, S] int32 (bool)
    const float* __restrict__ trans,   // [T, T] fp32
    float*       __restrict__ out)     // [1 + B]; we write out[1+b]
{
    const int b    = blockIdx.x;
    const int lane = threadIdx.x;
    const int j    = (lane < kT) ? lane : (kT - 1);  // clamp idle lanes

    __shared__ alignas(16) float tt_sh[kT * kTS];  // Tt[j][i] = trans[i][j]
    __shared__ alignas(16) float p_sh[64];         // part_i
    __shared__ alignas(16) float ea_sh[64];        // exp(part_i - e_i - M_i)
    const float4* p4  = (const float4*)p_sh;
    const float4* q4  = (const float4*)ea_sh;
    const float4* t4j = (const float4*)(tt_sh + (size_t)j * kTS);

    // E column as 24 packed float2 in regs; T column into LDS (transposed).
    REP24(DECL_EV)
    REP24(INIT_EV)

    const float* fb = feats + (size_t)b * kS * kT + j;  // lane-offset base
    const int*   mb = mask  + (size_t)b * kS;

    // part0 = emit[0] + transition[T-2, :]   (row 46, column j)
    float part = fb[0] + trans[(kT - 2) * kT + j];
    p_sh[lane] = part;
    wave_fence();   // order init tt_sh/p_sh writes before loop reads

    // Depth-4 register-rotated prefetch of emission only (mask is SALU now).
    float e0v = fb[(size_t)1 * kT], e1v = fb[(size_t)2 * kT],
          e2v = fb[(size_t)3 * kT], e3v = fb[(size_t)4 * kT];
    int mreg = mb[lane];   // mask words for steps 0..63 (coalesced)

    for (int blk = 0; blk < 16; ++blk) {
        // Uniform 64-step mask bitmask in an SGPR pair; per-step gate is
        // s_and/s_lshr + s_cbranch -- zero memory, zero VALU.
        unsigned long long bits = __ballot(mreg != 0);
        if (blk < 15) mreg = mb[(blk + 1) * 64 + lane];  // next block's word
        int t = blk * 64;
        const int tend = t + 64;
        if (blk == 0) { bits >>= 1; t = 1; }  // scan starts at step 1

        for (; t < tend; ++t) {
            const float e = e0v;
            e0v = e1v; e1v = e2v; e2v = e3v;
            const int tn = (t + 4 < kS) ? (t + 4) : (kS - 1);
            e3v = fb[(size_t)tn * kT];
            const bool mk = bits & 1ull;
            bits >>= 1;

            if (mk) {  // wave-uniform branch: skip masked-out steps
                const float pe = part - e;  // off the M-critical path

                // pass 1: M_j = max_i (T[i,j] + part_i)
                REP12(LOADT)
                REP12(LOADP)
                v2 mv0 = {-INFINITY, -INFINITY};
                v2 mv1 = mv0, mv2 = mv0, mv3 = mv0;
                REPQ(PASS1)
                mv0 = __builtin_elementwise_max(mv0, mv1);
                mv2 = __builtin_elementwise_max(mv2, mv3);
                mv0 = __builtin_elementwise_max(mv0, mv2);
                const float M = fmaxf(mv0.x, mv0.y);

                // lane i publishes exp(part_i - e_i - M_i)
                const float ea = __expf(pe - M);
                wave_fence();          // p_sh reads precede ea_sh write
                ea_sh[lane] = ea;
                wave_fence();          // ea_sh write precedes LOADQ reads

                // pass 2: S_j = sum_i exp(T[i,j]) * ea_i   (pk_fma chain)
                REP12(LOADQ)
                v2 sv0 = {0.f, 0.f};
                v2 sv1 = sv0, sv2 = sv0, sv3 = sv0;
                REPQ(PASS2)
                sv0 = sv0 + sv1;
                sv2 = sv2 + sv3;
                sv0 = sv0 + sv2;
                const float Ssum = sv0.x + sv0.y;

                part = 2.0f * e + M + __logf(Ssum);
                wave_fence();          // LOADQ reads precede p_sh overwrite
                p_sh[lane] = part;
                wave_fence();          // p_sh write precedes next LOADP
            }
        }
    }

    // Final transition-only step; only end_value[:, T-1] is stored.
    {
        REP12(LOADT)
        REP12(LOADP)
        v2 mv0 = {-INFINITY, -INFINITY};
        v2 mv1 = mv0, mv2 = mv0, mv3 = mv0;
        REPQ(PASS1)
        mv0 = __builtin_elementwise_max(mv0, mv1);
        mv2 = __builtin_elementwise_max(mv2, mv3);
        mv0 = __builtin_elementwise_max(mv0, mv2);
        const float M = fmaxf(mv0.x, mv0.y);
        const float ea = __expf(part - M);   // no emission in final step
        wave_fence();
        ea_sh[lane] = ea;
        wave_fence();

        REP12(LOADQ)
        v2 sv0 = {0.f, 0.f};
        v2 sv1 = sv0, sv2 = sv0, sv3 = sv0;
        REPQ(PASS2)
        sv0 = sv0 + sv1;
        sv2 = sv2 + sv3;
        sv0 = sv0 + sv2;
        const float Ssum = sv0.x + sv0.y;
        const float val = M + __logf(Ssum);
        if (lane == kT - 1) out[1 + b] = val;  // score[b] = end_value[b,-1]
    }
}

// out[0] = sum(score). Single wave; no barriers needed.
__global__ __launch_bounds__(64) void sum_scores(
    const float* __restrict__ sc, float* __restrict__ out)
{
    float s = 0.f;
    for (int i = (int)threadIdx.x; i < kB; i += 64) s += sc[i];
#pragma unroll
    for (int off = 32; off > 0; off >>= 1) s += __shfl_down(s, off);
    if (threadIdx.x == 0) out[0] = s;
}

extern "C" void kernel_launch(void* const* d_in, const int* in_sizes, int n_in,
                              void* d_out, int out_size, void* d_ws, size_t ws_size,
                              hipStream_t stream) {
    const float* feats = (const float*)d_in[0];
    const int*   mask  = (const int*)d_in[1];
    const float* trans = (const float*)d_in[2];
    float*       out   = (float*)d_out;

    crf_fwd<<<dim3(kB), dim3(64), 0, stream>>>(feats, mask, trans, out);
    sum_scores<<<dim3(1), dim3(64), 0, stream>>>(out + 1, out);
}